// Round 10
// baseline (319.033 us; speedup 1.0000x reference)
//
#include <hip/hip_runtime.h>

#define TPB 256
#define TE  2048      // edges per binscatter block
#define MAXB 6144     // max edges per coarse bucket (mean 4096)

typedef _Float16 half_t;
typedef _Float16 half2_t __attribute__((ext_vector_type(2)));
typedef _Float16 half4 __attribute__((ext_vector_type(4)));
typedef _Float16 half8 __attribute__((ext_vector_type(8)));
typedef float float8v __attribute__((ext_vector_type(8)));

static inline int cdiv(int a, int b) { return (a + b - 1) / b; }

// half8 . half8 with fp32 accumulate — v_dot2_f32_f16 (2 MACs/inst, fp32 acc)
__device__ __forceinline__ float dot8(half8 a, half8 b, float acc) {
#if __has_builtin(__builtin_amdgcn_fdot2)
    acc = __builtin_amdgcn_fdot2(half2_t{a[0], a[1]}, half2_t{b[0], b[1]}, acc, false);
    acc = __builtin_amdgcn_fdot2(half2_t{a[2], a[3]}, half2_t{b[2], b[3]}, acc, false);
    acc = __builtin_amdgcn_fdot2(half2_t{a[4], a[5]}, half2_t{b[4], b[5]}, acc, false);
    acc = __builtin_amdgcn_fdot2(half2_t{a[6], a[7]}, half2_t{b[6], b[7]}, acc, false);
#else
#pragma unroll
    for (int q = 0; q < 8; ++q) acc += (float)a[q] * (float)b[q];
#endif
    return acc;
}

// W[k][cg] (fp32, row-major K x CO) -> packed fp16 LDS layout where for fixed
// (k8=k>>3, j=cg&3) the 16B half8 blocks of consecutive col-groups c=cg>>2 are
// contiguous: idx = (((k8*4 + j)*CT) + c)*8 + (k&7).  Conflict-free b128 reads.
#define WPACK(k, cg, CT) (((((k) >> 3) * 4 + ((cg) & 3)) * (CT) + ((cg) >> 2)) * 8 + ((k) & 7))

// ---------------- CSR build: coalesced two-phase bucket sort ----------------
// Round-5 lesson: scattered 4B stores are ~16x write-amplified; NT hints make
// it worse. All global writes below are contiguous runs.

__global__ void k_zero_int(int* p, int n) {
    int i = blockIdx.x * blockDim.x + threadIdx.x;
    if (i < n) p[i] = 0;
}

__global__ void k_bhist(const int* __restrict__ dst, int* __restrict__ gcnt,
                        int e, int nb) {
    __shared__ int lc[256];
    for (int t = threadIdx.x; t < nb; t += TPB) lc[t] = 0;
    __syncthreads();
    for (int i = blockIdx.x * TPB + threadIdx.x; i < e; i += gridDim.x * TPB)
        atomicAdd(&lc[dst[i] >> 8], 1);
    __syncthreads();
    for (int t = threadIdx.x; t < nb; t += TPB) {
        int v = lc[t];
        if (v) atomicAdd(&gcnt[t], v);
    }
}

// bin edges into bucket regions; bucket bases computed by local scan of gcnt
__global__ void __launch_bounds__(TPB)
k_binscatter(const int* __restrict__ src, const int* __restrict__ dst,
             const int* __restrict__ gcnt, int* __restrict__ bcur2,
             unsigned int* __restrict__ gbuf, int e, int nb) {
    __shared__ int lcnt[256], loffs[256], lcur[256], gres[256];
    __shared__ int ss[256];
    __shared__ unsigned int ldata[TE];
    const int tid = threadIdx.x;
    const int base = blockIdx.x * TE;
    const int cnt = min(TE, e - base);

    {   // bucket global bases: exclusive scan of gcnt
        int v = (tid < nb) ? gcnt[tid] : 0;
        ss[tid] = v;
        __syncthreads();
        for (int d = 1; d < 256; d <<= 1) {
            int x2 = (tid >= d) ? ss[tid - d] : 0;
            __syncthreads();
            ss[tid] += x2;
            __syncthreads();
        }
        gres[tid] = ss[tid] - v;
        lcnt[tid] = 0;
    }
    __syncthreads();

    unsigned int myv[TE / TPB];
    int myb[TE / TPB];
#pragma unroll
    for (int k = 0; k < TE / TPB; ++k) {
        int j = tid + k * TPB;
        if (j < cnt) {
            int d = dst[base + j], s = src[base + j];
            int b = d >> 8;
            myv[k] = ((unsigned)b << 24) | ((unsigned)(d & 255) << 16) | (unsigned)s;
            myb[k] = b;
            atomicAdd(&lcnt[b], 1);
        } else myb[k] = -1;
    }
    __syncthreads();
    {   // scan lcnt -> loffs/lcur
        int v = (tid < nb) ? lcnt[tid] : 0;
        ss[tid] = v;
        __syncthreads();
        for (int d = 1; d < 256; d <<= 1) {
            int x2 = (tid >= d) ? ss[tid - d] : 0;
            __syncthreads();
            ss[tid] += x2;
            __syncthreads();
        }
        if (tid < nb) { loffs[tid] = ss[tid] - v; lcur[tid] = ss[tid] - v; }
    }
    __syncthreads();
    if (tid < nb && lcnt[tid]) gres[tid] += atomicAdd(&bcur2[tid], lcnt[tid]);
#pragma unroll
    for (int k = 0; k < TE / TPB; ++k) {
        if (myb[k] >= 0) {
            int p = atomicAdd(&lcur[myb[k]], 1);
            ldata[p] = myv[k];
        }
    }
    __syncthreads();
    for (int j = tid; j < cnt; j += TPB) {        // contiguous per-bucket runs
        unsigned int v = ldata[j];
        int b = v >> 24;
        gbuf[gres[b] + (j - loffs[b])] = v & 0xFFFFFFu;
    }
}

// per-bucket exact CSR (offs, dinv, ushort ssrc) + fused G = x*dinv scale
__global__ void __launch_bounds__(TPB)
k_csr(const unsigned int* __restrict__ gbuf, const int* __restrict__ gcnt,
      const float* __restrict__ x, int* __restrict__ offs,
      float* __restrict__ dinv, unsigned short* __restrict__ ssrc,
      half_t* __restrict__ G, int n, int e, int nb) {
    __shared__ int ss[256], cnt[256], loffs2[256], lcur2[256];
    __shared__ float sdinv[256];
    __shared__ unsigned short stage[MAXB];
    const int b = blockIdx.x;
    const int t = threadIdx.x;

    {   // bucket bounds from inclusive scan of gcnt
        int v = (t < nb) ? gcnt[t] : 0;
        ss[t] = v;
        __syncthreads();
        for (int d = 1; d < 256; d <<= 1) {
            int x2 = (t >= d) ? ss[t - d] : 0;
            __syncthreads();
            ss[t] += x2;
            __syncthreads();
        }
    }
    const int s0 = (b > 0) ? ss[b - 1] : 0;
    const int s1 = ss[b];
    const int m = s1 - s0;
    __syncthreads();
    cnt[t] = 0;
    __syncthreads();
    for (int j = t; j < m; j += TPB)
        atomicAdd(&cnt[(gbuf[s0 + j] >> 16) & 255], 1);
    __syncthreads();
    {
        int v = cnt[t];
        ss[t] = v;
        __syncthreads();
        for (int d = 1; d < 256; d <<= 1) {
            int x2 = (t >= d) ? ss[t - d] : 0;
            __syncthreads();
            ss[t] += x2;
            __syncthreads();
        }
        loffs2[t] = ss[t] - v;
        lcur2[t] = ss[t] - v;
        float di = rsqrtf((float)v + 1.0f);          // +1 self-loop
        sdinv[t] = di;
        int node = b * 256 + t;
        if (node < n) {
            offs[node] = s0 + loffs2[t];
            dinv[node] = di;
        }
    }
    __syncthreads();
    for (int j = t; j < m; j += TPB) {
        unsigned int v = gbuf[s0 + j];
        int p = atomicAdd(&lcur2[(v >> 16) & 255], 1);
        stage[p] = (unsigned short)(v & 0xFFFFu);
    }
    __syncthreads();
    for (int j = t; j < m; j += TPB) ssrc[s0 + j] = stage[j];
    if (b == 0 && t == 0) offs[n] = e;

    // fused scale: G[node] = x[node] * dinv[node], fp32 -> fp16
    const int base = b * 256;
    const int cn = min(256, n - base);
    const float4* X4 = (const float4*)x;
    half4* G4 = (half4*)G;
    for (int j = t; j < cn * 4; j += TPB) {
        int nl = j >> 2, k4 = j & 3;
        float4 v = X4[(size_t)(base + nl) * 4 + k4];
        float d = sdinv[nl];
        half4 h;
        h.x = (half_t)(v.x * d); h.y = (half_t)(v.y * d);
        h.z = (half_t)(v.z * d); h.w = (half_t)(v.w * d);
        G4[(size_t)(base + nl) * 4 + k4] = h;
    }
}

// ---------------- fused gather + GEMM conv ----------------
// Round-7 lesson: gather is latency-bound -> 4-way unroll + launch_bounds(,4).
// Round-9 lesson: degree-sorting rows was neutral-to-negative (stalled lanes
// are free in a latency-bound wave) -> removed.
// Round-10: FDOT path (conv3): fp16 X-tile + packed fp16 W + v_dot2_f32_f16
// halves GEMM-phase VALU instructions at full fp32 accumulation.
template<int DI, int DO, int R, bool SCALE, bool OUT_HALF, bool FDOT>
__global__ void __launch_bounds__(TPB, 4)
k_conv(const int* __restrict__ offs, const unsigned short* __restrict__ ssrc,
       const half_t* __restrict__ G, const float* __restrict__ dinv,
       const float* __restrict__ W, const float* __restrict__ b,
       void* __restrict__ outp, int n) {
    constexpr int CT = DO / 4;
    constexpr int RT = TPB / CT;
    constexpr int TM = RT * R;
    constexpr int K4 = DI / 4;
    constexpr int K8 = DI / 8;
    constexpr int PX = K4 + 1;       // fp32 tile pitch (float4)
    constexpr int XP = DI + 8;       // fp16 tile pitch (halfs; 16B-multiple)
    constexpr int C  = DI / 8;
    static_assert(TM * C == TPB, "gather/gemm tile mismatch");
    __shared__ __align__(16) float4 sW4[FDOT ? 1 : DI * CT];
    __shared__ __align__(16) half_t sWp[FDOT ? DI * DO : 8];
    __shared__ __align__(16) float4 sX4[FDOT ? 1 : TM * PX];
    __shared__ __align__(16) half_t sXh[FDOT ? TM * XP : 8];
    __shared__ int soffs[TM + 1];
    const int tid = threadIdx.x;
    const int r0 = blockIdx.x * TM;

    if (FDOT) {
        for (int t = tid; t < DI * DO; t += TPB) {
            int k = t / DO, cg = t - k * DO;          // W row-major [DI][DO]
            sWp[WPACK(k, cg, CT)] = (half_t)W[t];
        }
    } else {
        const float4* Wg = (const float4*)W;
        for (int t = tid; t < DI * CT; t += TPB) sW4[t] = Wg[t];
    }
    if (tid <= TM) soffs[tid] = offs[min(r0 + tid, n)];
    __syncthreads();

    // ---- gather phase: each thread aggregates one half8 chunk of one row ----
    {
        int lrow = tid / C;
        int gc = tid - lrow * C;
        int row = r0 + lrow;
        float8v acc;
#pragma unroll
        for (int q = 0; q < 8; ++q) acc[q] = 0.f;
        if (row < n) {
            const half8* Grow = (const half8*)G;
            half8 hs = Grow[(size_t)row * C + gc];
#pragma unroll
            for (int q = 0; q < 8; ++q) acc[q] = (float)hs[q];
            int s0 = soffs[lrow], s1 = soffs[lrow + 1];
            int j = s0;
            for (; j + 3 < s1; j += 4) {             // 4 loads in flight
                int sa = ssrc[j], sb = ssrc[j + 1];
                int sc = ssrc[j + 2], sd = ssrc[j + 3];
                half8 ga = Grow[(size_t)sa * C + gc];
                half8 gb = Grow[(size_t)sb * C + gc];
                half8 gch = Grow[(size_t)sc * C + gc];
                half8 gd = Grow[(size_t)sd * C + gc];
#pragma unroll
                for (int q = 0; q < 8; ++q)
                    acc[q] += ((float)ga[q] + (float)gb[q]) + ((float)gch[q] + (float)gd[q]);
            }
            for (; j < s1; ++j) {
                half8 ga = Grow[(size_t)ssrc[j] * C + gc];
#pragma unroll
                for (int q = 0; q < 8; ++q) acc[q] += (float)ga[q];
            }
            float di = dinv[row];
#pragma unroll
            for (int q = 0; q < 8; ++q) acc[q] *= di;
        }
        if (FDOT) {
            half8 h;
#pragma unroll
            for (int q = 0; q < 8; ++q) h[q] = (half_t)acc[q];
            *(half8*)&sXh[lrow * XP + gc * 8] = h;
        } else {
            sX4[lrow * PX + 2 * gc]     = make_float4(acc[0], acc[1], acc[2], acc[3]);
            sX4[lrow * PX + 2 * gc + 1] = make_float4(acc[4], acc[5], acc[6], acc[7]);
        }
    }
    __syncthreads();

    // ---- GEMM phase ----
    const int c = tid & (CT - 1);
    const int rg = tid / CT;
    const int rbase = rg * R;
    float accf[R][4];
#pragma unroll
    for (int r = 0; r < R; ++r)
#pragma unroll
        for (int j = 0; j < 4; ++j) accf[r][j] = 0.f;

    if (FDOT) {
#pragma unroll
        for (int k8 = 0; k8 < K8; ++k8) {
            half8 xh[R];
#pragma unroll
            for (int r = 0; r < R; ++r)
                xh[r] = *(const half8*)&sXh[(rbase + r) * XP + k8 * 8];
            half8 wv[4];
#pragma unroll
            for (int j = 0; j < 4; ++j)
                wv[j] = *(const half8*)&sWp[(((k8 * 4 + j) * CT) + c) * 8];
#pragma unroll
            for (int j = 0; j < 4; ++j)
#pragma unroll
                for (int r = 0; r < R; ++r)
                    accf[r][j] = dot8(xh[r], wv[j], accf[r][j]);
        }
    } else {
#pragma unroll 2
        for (int k4 = 0; k4 < K4; ++k4) {
            float4 xv[R];
#pragma unroll
            for (int r = 0; r < R; ++r) xv[r] = sX4[(rbase + r) * PX + k4];
#pragma unroll
            for (int kk = 0; kk < 4; ++kk) {
                float4 wv = sW4[(k4 * 4 + kk) * CT + c];
#pragma unroll
                for (int r = 0; r < R; ++r) {
                    float xs = (kk == 0) ? xv[r].x : (kk == 1) ? xv[r].y
                             : (kk == 2) ? xv[r].z : xv[r].w;
                    accf[r][0] += xs * wv.x; accf[r][1] += xs * wv.y;
                    accf[r][2] += xs * wv.z; accf[r][3] += xs * wv.w;
                }
            }
        }
    }

    float4 bc = ((const float4*)b)[c];
#pragma unroll
    for (int r = 0; r < R; ++r) {
        int row = r0 + rbase + r;
        if (row < n) {
            float4 o;
            o.x = fmaxf(accf[r][0] + bc.x, 0.f);
            o.y = fmaxf(accf[r][1] + bc.y, 0.f);
            o.z = fmaxf(accf[r][2] + bc.z, 0.f);
            o.w = fmaxf(accf[r][3] + bc.w, 0.f);
            if (SCALE) {
                float d = dinv[row];
                o.x *= d; o.y *= d; o.z *= d; o.w *= d;
            }
            if (OUT_HALF) {
                half4 h;
                h.x = (half_t)o.x; h.y = (half_t)o.y;
                h.z = (half_t)o.z; h.w = (half_t)o.w;
                ((half4*)outp)[(size_t)row * CT + c] = h;
            } else {
                ((float4*)outp)[(size_t)row * CT + c] = o;
            }
        }
    }
}

// ---------------- fused dense head ----------------
// Stage 1 (77% of head FLOPs) uses fdot2 on already-fp16 X3h and fp16 W1 —
// numerically identical to the prior fp32-convert FMA path, half the insts.
__global__ void __launch_bounds__(256, 2)
k_head(const half_t* __restrict__ X,
       const float* __restrict__ W1, const float* __restrict__ b1,
       const float* __restrict__ W2, const float* __restrict__ b2,
       const float* __restrict__ W3, const float* __restrict__ b3,
       float* __restrict__ out, int n) {
    __shared__ __align__(16) half_t hW1p[128 * 64];   // packed for fdot2
    __shared__ half_t hW2[64 * 32];
    __shared__ half_t hW3[32 * 16];
    __shared__ float h1[64 * 65];
    __shared__ float h2[64 * 33];
    const int tid = threadIdx.x;
    const int r0 = blockIdx.x * 64;

    for (int t = tid; t < 128 * 64; t += 256) {
        int k = t >> 6, cg = t & 63;                  // W1 row-major [128][64]
        hW1p[WPACK(k, cg, 16)] = (half_t)W1[t];
    }
    for (int t = tid; t < 64 * 32; t += 256) hW2[t] = (half_t)W2[t];
    for (int t = tid; t < 32 * 16; t += 256) hW3[t] = (half_t)W3[t];
    __syncthreads();

    // ---- stage 1: 128 -> 64, fdot2 ----
    {
        const int c4 = tid & 15;          // float4 col-group of 64
        const int rowg = tid >> 4;        // 0..15 -> rows rowg*4..+3
        const half8* Xr = (const half8*)X;
        float acc[4][4];
#pragma unroll
        for (int r = 0; r < 4; ++r)
#pragma unroll
            for (int j = 0; j < 4; ++j) acc[r][j] = 0.f;
#pragma unroll 4
        for (int k8 = 0; k8 < 16; ++k8) {
            half8 xh[4];
#pragma unroll
            for (int r = 0; r < 4; ++r) {
                int row = r0 + rowg * 4 + r;
                if (row < n) xh[r] = Xr[(size_t)row * 16 + k8];
                else { half8 z; for (int q = 0; q < 8; ++q) z[q] = (half_t)0.f; xh[r] = z; }
            }
            half8 wv[4];
#pragma unroll
            for (int j = 0; j < 4; ++j)
                wv[j] = *(const half8*)&hW1p[(((k8 * 4 + j) * 16) + c4) * 8];
#pragma unroll
            for (int j = 0; j < 4; ++j)
#pragma unroll
                for (int r = 0; r < 4; ++r)
                    acc[r][j] = dot8(xh[r], wv[j], acc[r][j]);
        }
        float4 bc = ((const float4*)b1)[c4];
#pragma unroll
        for (int r = 0; r < 4; ++r) {
            int rl = rowg * 4 + r;
            h1[rl * 65 + c4 * 4 + 0] = fmaxf(acc[r][0] + bc.x, 0.f);
            h1[rl * 65 + c4 * 4 + 1] = fmaxf(acc[r][1] + bc.y, 0.f);
            h1[rl * 65 + c4 * 4 + 2] = fmaxf(acc[r][2] + bc.z, 0.f);
            h1[rl * 65 + c4 * 4 + 3] = fmaxf(acc[r][3] + bc.w, 0.f);
        }
    }
    __syncthreads();

    // ---- stage 2: 64 -> 32 ----
    {
        const int c4 = tid & 7;
        const int rowg = tid >> 3;
        float acc[2][4];
#pragma unroll
        for (int r = 0; r < 2; ++r)
#pragma unroll
            for (int j = 0; j < 4; ++j) acc[r][j] = 0.f;
#pragma unroll 4
        for (int k = 0; k < 64; ++k) {
            half4 w = *(const half4*)&hW2[k * 32 + c4 * 4];
            float w0 = (float)w.x, w1 = (float)w.y, w2 = (float)w.z, w3 = (float)w.w;
#pragma unroll
            for (int r = 0; r < 2; ++r) {
                float xs = h1[(rowg * 2 + r) * 65 + k];
                acc[r][0] += xs * w0; acc[r][1] += xs * w1;
                acc[r][2] += xs * w2; acc[r][3] += xs * w3;
            }
        }
        float4 bc = ((const float4*)b2)[c4];
#pragma unroll
        for (int r = 0; r < 2; ++r) {
            int rl = rowg * 2 + r;
            h2[rl * 33 + c4 * 4 + 0] = fmaxf(acc[r][0] + bc.x, 0.f);
            h2[rl * 33 + c4 * 4 + 1] = fmaxf(acc[r][1] + bc.y, 0.f);
            h2[rl * 33 + c4 * 4 + 2] = fmaxf(acc[r][2] + bc.z, 0.f);
            h2[rl * 33 + c4 * 4 + 3] = fmaxf(acc[r][3] + bc.w, 0.f);
        }
    }
    __syncthreads();

    // ---- stage 3: 32 -> 16 ----
    {
        const int c4 = tid & 3;
        const int rl = tid >> 2;
        float a0 = 0.f, a1 = 0.f, a2 = 0.f, a3 = 0.f;
#pragma unroll 4
        for (int k = 0; k < 32; ++k) {
            half4 w = *(const half4*)&hW3[k * 16 + c4 * 4];
            float xs = h2[rl * 33 + k];
            a0 += xs * (float)w.x; a1 += xs * (float)w.y;
            a2 += xs * (float)w.z; a3 += xs * (float)w.w;
        }
        int row = r0 + rl;
        if (row < n) {
            float4 bc = ((const float4*)b3)[c4];
            float4 o;
            o.x = fmaxf(a0 + bc.x, 0.f);
            o.y = fmaxf(a1 + bc.y, 0.f);
            o.z = fmaxf(a2 + bc.z, 0.f);
            o.w = fmaxf(a3 + bc.w, 0.f);
            ((float4*)out)[(size_t)row * 4 + c4] = o;
        }
    }
}

extern "C" void kernel_launch(void* const* d_in, const int* in_sizes, int n_in,
                              void* d_out, int out_size, void* d_ws, size_t ws_size,
                              hipStream_t stream) {
    const float* x   = (const float*)d_in[0];
    const int*   ei  = (const int*)d_in[1];
    const float* W1  = (const float*)d_in[2];
    const float* bb1 = (const float*)d_in[3];
    const float* W2  = (const float*)d_in[4];
    const float* bb2 = (const float*)d_in[5];
    const float* W3  = (const float*)d_in[6];
    const float* bb3 = (const float*)d_in[7];
    const float* Wl1 = (const float*)d_in[8];
    const float* bl1 = (const float*)d_in[9];
    const float* Wl2 = (const float*)d_in[10];
    const float* bl2 = (const float*)d_in[11];
    const float* Wl3 = (const float*)d_in[12];
    const float* bl3 = (const float*)d_in[13];
    float* out = (float*)d_out;

    const int n = in_sizes[0] / 16;   // 50000
    const int e = in_sizes[1] / 2;    // 800000
    const int* src = ei;
    const int* dst = ei + e;
    const int nb = cdiv(n, 256);      // 196 coarse buckets

    char* p = (char*)d_ws;
    auto alloc = [&](size_t bytes) {
        char* r = p;
        p += (bytes + 255) & ~(size_t)255;
        return r;
    };
    float*          dinv   = (float*)         alloc((size_t)n * 4);
    int*            offs   = (int*)           alloc((size_t)(n + 1) * 4);
    int*            gcnt   = (int*)           alloc(256 * 4);   // adjacent:
    int*            bcur2  = (int*)           alloc(256 * 4);   // zeroed together
    unsigned int*   gbuf   = (unsigned int*)  alloc((size_t)e * 4);
    unsigned short* ssrc   = (unsigned short*)alloc((size_t)e * 2);
    half_t*         H1     = (half_t*)        alloc((size_t)n * 64 * 2);  // also G(16)
    half_t*         H2     = (half_t*)        alloc((size_t)n * 32 * 2);
    half_t*         X3h    = (half_t*)        alloc((size_t)n * 128 * 2);

    // ---- CSR + dinv + scaled G (all-coalesced bucket sort) ----
    k_zero_int<<<2, 256, 0, stream>>>(gcnt, 512);            // gcnt + bcur2
    k_bhist<<<512, TPB, 0, stream>>>(dst, gcnt, e, nb);
    k_binscatter<<<cdiv(e, TE), TPB, 0, stream>>>(src, dst, gcnt, bcur2, gbuf, e, nb);
    k_csr<<<nb, TPB, 0, stream>>>(gbuf, gcnt, x, offs, dinv, ssrc, H1, n, e, nb);

    // ---- convs (fused gather+GEMM) ----
    k_conv<16, 32, 4, true, true, false><<<cdiv(n, 128), TPB, 0, stream>>>(
        offs, ssrc, H1, dinv, W1, bb1, H2, n);
    k_conv<32, 64, 4, true, true, false><<<cdiv(n, 64), TPB, 0, stream>>>(
        offs, ssrc, H2, dinv, W2, bb2, H1, n);
    k_conv<64, 128, 4, false, true, true><<<cdiv(n, 32), TPB, 0, stream>>>(
        offs, ssrc, H1, dinv, W3, bb3, X3h, n);

    // ---- fused dense head ----
    k_head<<<cdiv(n, 64), 256, 0, stream>>>(X3h, Wl1, bl1, Wl2, bl2, Wl3, bl3, out, n);
}

// Round 11
// 214.649 us; speedup vs baseline: 1.4863x; 1.4863x over previous
//
#include <hip/hip_runtime.h>

#define TPB 256
#define TE  2048      // edges per binscatter block
#define MAXB 6144     // max edges per coarse bucket (mean 4096)

typedef _Float16 half_t;
typedef _Float16 half4 __attribute__((ext_vector_type(4)));
typedef _Float16 half8 __attribute__((ext_vector_type(8)));
typedef float float8v __attribute__((ext_vector_type(8)));

static inline int cdiv(int a, int b) { return (a + b - 1) / b; }

// ---------------- CSR build: coalesced two-phase bucket sort ----------------
// Round-5 lesson: scattered 4B stores are ~16x write-amplified; NT hints make
// it worse. All global writes below are contiguous runs.

__global__ void k_zero_int(int* p, int n) {
    int i = blockIdx.x * blockDim.x + threadIdx.x;
    if (i < n) p[i] = 0;
}

__global__ void k_bhist(const int* __restrict__ dst, int* __restrict__ gcnt,
                        int e, int nb) {
    __shared__ int lc[256];
    for (int t = threadIdx.x; t < nb; t += TPB) lc[t] = 0;
    __syncthreads();
    for (int i = blockIdx.x * TPB + threadIdx.x; i < e; i += gridDim.x * TPB)
        atomicAdd(&lc[dst[i] >> 8], 1);
    __syncthreads();
    for (int t = threadIdx.x; t < nb; t += TPB) {
        int v = lc[t];
        if (v) atomicAdd(&gcnt[t], v);
    }
}

// bin edges into bucket regions; bucket bases computed by local scan of gcnt
__global__ void __launch_bounds__(TPB)
k_binscatter(const int* __restrict__ src, const int* __restrict__ dst,
             const int* __restrict__ gcnt, int* __restrict__ bcur2,
             unsigned int* __restrict__ gbuf, int e, int nb) {
    __shared__ int lcnt[256], loffs[256], lcur[256], gres[256];
    __shared__ int ss[256];
    __shared__ unsigned int ldata[TE];
    const int tid = threadIdx.x;
    const int base = blockIdx.x * TE;
    const int cnt = min(TE, e - base);

    {   // bucket global bases: exclusive scan of gcnt
        int v = (tid < nb) ? gcnt[tid] : 0;
        ss[tid] = v;
        __syncthreads();
        for (int d = 1; d < 256; d <<= 1) {
            int x2 = (tid >= d) ? ss[tid - d] : 0;
            __syncthreads();
            ss[tid] += x2;
            __syncthreads();
        }
        gres[tid] = ss[tid] - v;
        lcnt[tid] = 0;
    }
    __syncthreads();

    unsigned int myv[TE / TPB];
    int myb[TE / TPB];
#pragma unroll
    for (int k = 0; k < TE / TPB; ++k) {
        int j = tid + k * TPB;
        if (j < cnt) {
            int d = dst[base + j], s = src[base + j];
            int b = d >> 8;
            myv[k] = ((unsigned)b << 24) | ((unsigned)(d & 255) << 16) | (unsigned)s;
            myb[k] = b;
            atomicAdd(&lcnt[b], 1);
        } else myb[k] = -1;
    }
    __syncthreads();
    {   // scan lcnt -> loffs/lcur
        int v = (tid < nb) ? lcnt[tid] : 0;
        ss[tid] = v;
        __syncthreads();
        for (int d = 1; d < 256; d <<= 1) {
            int x2 = (tid >= d) ? ss[tid - d] : 0;
            __syncthreads();
            ss[tid] += x2;
            __syncthreads();
        }
        if (tid < nb) { loffs[tid] = ss[tid] - v; lcur[tid] = ss[tid] - v; }
    }
    __syncthreads();
    if (tid < nb && lcnt[tid]) gres[tid] += atomicAdd(&bcur2[tid], lcnt[tid]);
#pragma unroll
    for (int k = 0; k < TE / TPB; ++k) {
        if (myb[k] >= 0) {
            int p = atomicAdd(&lcur[myb[k]], 1);
            ldata[p] = myv[k];
        }
    }
    __syncthreads();
    for (int j = tid; j < cnt; j += TPB) {        // contiguous per-bucket runs
        unsigned int v = ldata[j];
        int b = v >> 24;
        gbuf[gres[b] + (j - loffs[b])] = v & 0xFFFFFFu;
    }
}

// per-bucket exact CSR (offs, dinv, ushort ssrc) + fused G = x*dinv scale
__global__ void __launch_bounds__(TPB)
k_csr(const unsigned int* __restrict__ gbuf, const int* __restrict__ gcnt,
      const float* __restrict__ x, int* __restrict__ offs,
      float* __restrict__ dinv, unsigned short* __restrict__ ssrc,
      half_t* __restrict__ G, int n, int e, int nb) {
    __shared__ int ss[256], cnt[256], loffs2[256], lcur2[256];
    __shared__ float sdinv[256];
    __shared__ unsigned short stage[MAXB];
    const int b = blockIdx.x;
    const int t = threadIdx.x;

    {   // bucket bounds from inclusive scan of gcnt
        int v = (t < nb) ? gcnt[t] : 0;
        ss[t] = v;
        __syncthreads();
        for (int d = 1; d < 256; d <<= 1) {
            int x2 = (t >= d) ? ss[t - d] : 0;
            __syncthreads();
            ss[t] += x2;
            __syncthreads();
        }
    }
    const int s0 = (b > 0) ? ss[b - 1] : 0;
    const int s1 = ss[b];
    const int m = s1 - s0;
    __syncthreads();
    cnt[t] = 0;
    __syncthreads();
    for (int j = t; j < m; j += TPB)
        atomicAdd(&cnt[(gbuf[s0 + j] >> 16) & 255], 1);
    __syncthreads();
    {
        int v = cnt[t];
        ss[t] = v;
        __syncthreads();
        for (int d = 1; d < 256; d <<= 1) {
            int x2 = (t >= d) ? ss[t - d] : 0;
            __syncthreads();
            ss[t] += x2;
            __syncthreads();
        }
        loffs2[t] = ss[t] - v;
        lcur2[t] = ss[t] - v;
        float di = rsqrtf((float)v + 1.0f);          // +1 self-loop
        sdinv[t] = di;
        int node = b * 256 + t;
        if (node < n) {
            offs[node] = s0 + loffs2[t];
            dinv[node] = di;
        }
    }
    __syncthreads();
    for (int j = t; j < m; j += TPB) {
        unsigned int v = gbuf[s0 + j];
        int p = atomicAdd(&lcur2[(v >> 16) & 255], 1);
        stage[p] = (unsigned short)(v & 0xFFFFu);
    }
    __syncthreads();
    for (int j = t; j < m; j += TPB) ssrc[s0 + j] = stage[j];
    if (b == 0 && t == 0) offs[n] = e;

    // fused scale: G[node] = x[node] * dinv[node], fp32 -> fp16
    const int base = b * 256;
    const int cn = min(256, n - base);
    const float4* X4 = (const float4*)x;
    half4* G4 = (half4*)G;
    for (int j = t; j < cn * 4; j += TPB) {
        int nl = j >> 2, k4 = j & 3;
        float4 v = X4[(size_t)(base + nl) * 4 + k4];
        float d = sdinv[nl];
        half4 h;
        h.x = (half_t)(v.x * d); h.y = (half_t)(v.y * d);
        h.z = (half_t)(v.z * d); h.w = (half_t)(v.w * d);
        G4[(size_t)(base + nl) * 4 + k4] = h;
    }
}

// ---------------- fused gather + GEMM conv (round-8 proven structure) ----------
// Round-7 lesson: gather is latency-bound -> deep unroll + launch_bounds(,4).
// Round-9 lesson: degree-sorting rows is neutral/negative -> not here.
// Round-10 lesson: FDOT/packed-fp16 GEMM phase spills (VGPR 64, 540 MB scratch
// traffic) -> fp32 LDS GEMM path only. Round-11: 8-way gather unroll (mean
// degree 16 -> 2 batches of 8 loads in flight instead of 4 of 4).
template<int DI, int DO, int R, bool SCALE, bool OUT_HALF, bool WHALF>
__global__ void __launch_bounds__(TPB, 4)
k_conv(const int* __restrict__ offs, const unsigned short* __restrict__ ssrc,
       const half_t* __restrict__ G, const float* __restrict__ dinv,
       const float* __restrict__ W, const float* __restrict__ b,
       void* __restrict__ outp, int n) {
    constexpr int CT = DO / 4;
    constexpr int RT = TPB / CT;
    constexpr int TM = RT * R;
    constexpr int K4 = DI / 4;
    constexpr int PX = K4 + 1;       // padded pitch
    constexpr int C  = DI / 8;
    static_assert(TM * C == TPB, "gather/gemm tile mismatch");
    __shared__ float4 sW4[WHALF ? 1 : DI * CT];
    __shared__ half4  sWh[WHALF ? DI * CT : 1];
    __shared__ float4 sX4[TM * PX];
    __shared__ int soffs[TM + 1];
    const int tid = threadIdx.x;
    const int r0 = blockIdx.x * TM;

    const float4* Wg = (const float4*)W;
    for (int t = tid; t < DI * CT; t += TPB) {
        float4 w = Wg[t];
        if (WHALF) {
            half4 h;
            h.x = (half_t)w.x; h.y = (half_t)w.y;
            h.z = (half_t)w.z; h.w = (half_t)w.w;
            sWh[t] = h;
        } else {
            sW4[t] = w;
        }
    }
    if (tid <= TM) soffs[tid] = offs[min(r0 + tid, n)];
    __syncthreads();

    // ---- gather phase: each thread aggregates one half8 chunk of one row ----
    {
        int lrow = tid / C;
        int gc = tid - lrow * C;
        int row = r0 + lrow;
        float8v acc;
#pragma unroll
        for (int q = 0; q < 8; ++q) acc[q] = 0.f;
        if (row < n) {
            const half8* Grow = (const half8*)G;
            half8 hs = Grow[(size_t)row * C + gc];
#pragma unroll
            for (int q = 0; q < 8; ++q) acc[q] = (float)hs[q];
            int s0 = soffs[lrow], s1 = soffs[lrow + 1];
            int j = s0;
            for (; j + 7 < s1; j += 8) {             // 8 loads in flight
                half8 g0 = Grow[(size_t)ssrc[j + 0] * C + gc];
                half8 g1 = Grow[(size_t)ssrc[j + 1] * C + gc];
                half8 g2 = Grow[(size_t)ssrc[j + 2] * C + gc];
                half8 g3 = Grow[(size_t)ssrc[j + 3] * C + gc];
                half8 g4 = Grow[(size_t)ssrc[j + 4] * C + gc];
                half8 g5 = Grow[(size_t)ssrc[j + 5] * C + gc];
                half8 g6 = Grow[(size_t)ssrc[j + 6] * C + gc];
                half8 g7 = Grow[(size_t)ssrc[j + 7] * C + gc];
#pragma unroll
                for (int q = 0; q < 8; ++q)
                    acc[q] += (((float)g0[q] + (float)g1[q]) + ((float)g2[q] + (float)g3[q]))
                            + (((float)g4[q] + (float)g5[q]) + ((float)g6[q] + (float)g7[q]));
            }
            for (; j + 3 < s1; j += 4) {
                half8 g0 = Grow[(size_t)ssrc[j + 0] * C + gc];
                half8 g1 = Grow[(size_t)ssrc[j + 1] * C + gc];
                half8 g2 = Grow[(size_t)ssrc[j + 2] * C + gc];
                half8 g3 = Grow[(size_t)ssrc[j + 3] * C + gc];
#pragma unroll
                for (int q = 0; q < 8; ++q)
                    acc[q] += ((float)g0[q] + (float)g1[q]) + ((float)g2[q] + (float)g3[q]);
            }
            for (; j < s1; ++j) {
                half8 ga = Grow[(size_t)ssrc[j] * C + gc];
#pragma unroll
                for (int q = 0; q < 8; ++q) acc[q] += (float)ga[q];
            }
            float di = dinv[row];
#pragma unroll
            for (int q = 0; q < 8; ++q) acc[q] *= di;
        }
        sX4[lrow * PX + 2 * gc]     = make_float4(acc[0], acc[1], acc[2], acc[3]);
        sX4[lrow * PX + 2 * gc + 1] = make_float4(acc[4], acc[5], acc[6], acc[7]);
    }
    __syncthreads();

    // ---- GEMM phase (fp32 LDS, round-8 proven) ----
    const int c = tid & (CT - 1);
    const int rg = tid / CT;
    const int rbase = rg * R;
    float4 acc[R];
#pragma unroll
    for (int r = 0; r < R; ++r) acc[r] = make_float4(0.f, 0.f, 0.f, 0.f);

#pragma unroll 2
    for (int k4 = 0; k4 < K4; ++k4) {
        float4 xv[R];
#pragma unroll
        for (int r = 0; r < R; ++r) xv[r] = sX4[(rbase + r) * PX + k4];
#pragma unroll
        for (int kk = 0; kk < 4; ++kk) {
            float4 wv;
            if (WHALF) {
                half4 wh = sWh[(k4 * 4 + kk) * CT + c];
                wv = make_float4((float)wh.x, (float)wh.y, (float)wh.z, (float)wh.w);
            } else {
                wv = sW4[(k4 * 4 + kk) * CT + c];
            }
#pragma unroll
            for (int r = 0; r < R; ++r) {
                float xs = (kk == 0) ? xv[r].x : (kk == 1) ? xv[r].y
                         : (kk == 2) ? xv[r].z : xv[r].w;
                acc[r].x += xs * wv.x; acc[r].y += xs * wv.y;
                acc[r].z += xs * wv.z; acc[r].w += xs * wv.w;
            }
        }
    }

    float4 bc = ((const float4*)b)[c];
#pragma unroll
    for (int r = 0; r < R; ++r) {
        int row = r0 + rbase + r;
        if (row < n) {
            float4 o;
            o.x = fmaxf(acc[r].x + bc.x, 0.f);
            o.y = fmaxf(acc[r].y + bc.y, 0.f);
            o.z = fmaxf(acc[r].z + bc.z, 0.f);
            o.w = fmaxf(acc[r].w + bc.w, 0.f);
            if (SCALE) {
                float d = dinv[row];
                o.x *= d; o.y *= d; o.z *= d; o.w *= d;
            }
            if (OUT_HALF) {
                half4 h;
                h.x = (half_t)o.x; h.y = (half_t)o.y;
                h.z = (half_t)o.z; h.w = (half_t)o.w;
                ((half4*)outp)[(size_t)row * CT + c] = h;
            } else {
                ((float4*)outp)[(size_t)row * CT + c] = o;
            }
        }
    }
}

// ---------------- fused dense head (round-8 proven) ----------------
__global__ void __launch_bounds__(256, 2)
k_head(const half_t* __restrict__ X,
       const float* __restrict__ W1, const float* __restrict__ b1,
       const float* __restrict__ W2, const float* __restrict__ b2,
       const float* __restrict__ W3, const float* __restrict__ b3,
       float* __restrict__ out, int n) {
    __shared__ half_t hW1[128 * 64];
    __shared__ half_t hW2[64 * 32];
    __shared__ half_t hW3[32 * 16];
    __shared__ float h1[64 * 65];
    __shared__ float h2[64 * 33];
    const int tid = threadIdx.x;
    const int r0 = blockIdx.x * 64;

    for (int t = tid; t < 128 * 64; t += 256) hW1[t] = (half_t)W1[t];
    for (int t = tid; t < 64 * 32; t += 256) hW2[t] = (half_t)W2[t];
    for (int t = tid; t < 32 * 16; t += 256) hW3[t] = (half_t)W3[t];
    __syncthreads();

    // ---- stage 1: 128 -> 64 ----
    {
        const int c4 = tid & 15;
        const int rowg = tid >> 4;
        const half8* Xr = (const half8*)X;
        float acc[4][4];
#pragma unroll
        for (int r = 0; r < 4; ++r)
#pragma unroll
            for (int j = 0; j < 4; ++j) acc[r][j] = 0.f;
        for (int k8 = 0; k8 < 16; ++k8) {
            half8 xh[4];
#pragma unroll
            for (int r = 0; r < 4; ++r) {
                int row = r0 + rowg * 4 + r;
                if (row < n) xh[r] = Xr[(size_t)row * 16 + k8];
                else { half8 z; for (int q = 0; q < 8; ++q) z[q] = (half_t)0.f; xh[r] = z; }
            }
#pragma unroll
            for (int q = 0; q < 8; ++q) {
                int k = k8 * 8 + q;
                half4 w = *(const half4*)&hW1[k * 64 + c4 * 4];
                float w0 = (float)w.x, w1 = (float)w.y, w2 = (float)w.z, w3 = (float)w.w;
#pragma unroll
                for (int r = 0; r < 4; ++r) {
                    float xs = (float)xh[r][q];
                    acc[r][0] += xs * w0; acc[r][1] += xs * w1;
                    acc[r][2] += xs * w2; acc[r][3] += xs * w3;
                }
            }
        }
        float4 bc = ((const float4*)b1)[c4];
#pragma unroll
        for (int r = 0; r < 4; ++r) {
            int rl = rowg * 4 + r;
            h1[rl * 65 + c4 * 4 + 0] = fmaxf(acc[r][0] + bc.x, 0.f);
            h1[rl * 65 + c4 * 4 + 1] = fmaxf(acc[r][1] + bc.y, 0.f);
            h1[rl * 65 + c4 * 4 + 2] = fmaxf(acc[r][2] + bc.z, 0.f);
            h1[rl * 65 + c4 * 4 + 3] = fmaxf(acc[r][3] + bc.w, 0.f);
        }
    }
    __syncthreads();

    // ---- stage 2: 64 -> 32 ----
    {
        const int c4 = tid & 7;
        const int rowg = tid >> 3;
        float acc[2][4];
#pragma unroll
        for (int r = 0; r < 2; ++r)
#pragma unroll
            for (int j = 0; j < 4; ++j) acc[r][j] = 0.f;
#pragma unroll 4
        for (int k = 0; k < 64; ++k) {
            half4 w = *(const half4*)&hW2[k * 32 + c4 * 4];
            float w0 = (float)w.x, w1 = (float)w.y, w2 = (float)w.z, w3 = (float)w.w;
#pragma unroll
            for (int r = 0; r < 2; ++r) {
                float xs = h1[(rowg * 2 + r) * 65 + k];
                acc[r][0] += xs * w0; acc[r][1] += xs * w1;
                acc[r][2] += xs * w2; acc[r][3] += xs * w3;
            }
        }
        float4 bc = ((const float4*)b2)[c4];
#pragma unroll
        for (int r = 0; r < 2; ++r) {
            int rl = rowg * 2 + r;
            h2[rl * 33 + c4 * 4 + 0] = fmaxf(acc[r][0] + bc.x, 0.f);
            h2[rl * 33 + c4 * 4 + 1] = fmaxf(acc[r][1] + bc.y, 0.f);
            h2[rl * 33 + c4 * 4 + 2] = fmaxf(acc[r][2] + bc.z, 0.f);
            h2[rl * 33 + c4 * 4 + 3] = fmaxf(acc[r][3] + bc.w, 0.f);
        }
    }
    __syncthreads();

    // ---- stage 3: 32 -> 16 ----
    {
        const int c4 = tid & 3;
        const int rl = tid >> 2;
        float a0 = 0.f, a1 = 0.f, a2 = 0.f, a3 = 0.f;
#pragma unroll 4
        for (int k = 0; k < 32; ++k) {
            half4 w = *(const half4*)&hW3[k * 16 + c4 * 4];
            float xs = h2[rl * 33 + k];
            a0 += xs * (float)w.x; a1 += xs * (float)w.y;
            a2 += xs * (float)w.z; a3 += xs * (float)w.w;
        }
        int row = r0 + rl;
        if (row < n) {
            float4 bc = ((const float4*)b3)[c4];
            float4 o;
            o.x = fmaxf(a0 + bc.x, 0.f);
            o.y = fmaxf(a1 + bc.y, 0.f);
            o.z = fmaxf(a2 + bc.z, 0.f);
            o.w = fmaxf(a3 + bc.w, 0.f);
            ((float4*)out)[(size_t)row * 4 + c4] = o;
        }
    }
}

extern "C" void kernel_launch(void* const* d_in, const int* in_sizes, int n_in,
                              void* d_out, int out_size, void* d_ws, size_t ws_size,
                              hipStream_t stream) {
    const float* x   = (const float*)d_in[0];
    const int*   ei  = (const int*)d_in[1];
    const float* W1  = (const float*)d_in[2];
    const float* bb1 = (const float*)d_in[3];
    const float* W2  = (const float*)d_in[4];
    const float* bb2 = (const float*)d_in[5];
    const float* W3  = (const float*)d_in[6];
    const float* bb3 = (const float*)d_in[7];
    const float* Wl1 = (const float*)d_in[8];
    const float* bl1 = (const float*)d_in[9];
    const float* Wl2 = (const float*)d_in[10];
    const float* bl2 = (const float*)d_in[11];
    const float* Wl3 = (const float*)d_in[12];
    const float* bl3 = (const float*)d_in[13];
    float* out = (float*)d_out;

    const int n = in_sizes[0] / 16;   // 50000
    const int e = in_sizes[1] / 2;    // 800000
    const int* src = ei;
    const int* dst = ei + e;
    const int nb = cdiv(n, 256);      // 196 coarse buckets

    char* p = (char*)d_ws;
    auto alloc = [&](size_t bytes) {
        char* r = p;
        p += (bytes + 255) & ~(size_t)255;
        return r;
    };
    float*          dinv   = (float*)         alloc((size_t)n * 4);
    int*            offs   = (int*)           alloc((size_t)(n + 1) * 4);
    int*            gcnt   = (int*)           alloc(256 * 4);   // adjacent:
    int*            bcur2  = (int*)           alloc(256 * 4);   // zeroed together
    unsigned int*   gbuf   = (unsigned int*)  alloc((size_t)e * 4);
    unsigned short* ssrc   = (unsigned short*)alloc((size_t)e * 2);
    half_t*         H1     = (half_t*)        alloc((size_t)n * 64 * 2);  // also G(16)
    half_t*         H2     = (half_t*)        alloc((size_t)n * 32 * 2);
    half_t*         X3h    = (half_t*)        alloc((size_t)n * 128 * 2);

    // ---- CSR + dinv + scaled G (all-coalesced bucket sort) ----
    k_zero_int<<<2, 256, 0, stream>>>(gcnt, 512);            // gcnt + bcur2
    k_bhist<<<512, TPB, 0, stream>>>(dst, gcnt, e, nb);
    k_binscatter<<<cdiv(e, TE), TPB, 0, stream>>>(src, dst, gcnt, bcur2, gbuf, e, nb);
    k_csr<<<nb, TPB, 0, stream>>>(gbuf, gcnt, x, offs, dinv, ssrc, H1, n, e, nb);

    // ---- convs (fused gather+GEMM) ----
    k_conv<16, 32, 4, true, true, false><<<cdiv(n, 128), TPB, 0, stream>>>(
        offs, ssrc, H1, dinv, W1, bb1, H2, n);
    k_conv<32, 64, 4, true, true, false><<<cdiv(n, 64), TPB, 0, stream>>>(
        offs, ssrc, H2, dinv, W2, bb2, H1, n);
    k_conv<64, 128, 4, false, true, true><<<cdiv(n, 32), TPB, 0, stream>>>(
        offs, ssrc, H1, dinv, W3, bb3, X3h, n);

    // ---- fused dense head ----
    k_head<<<cdiv(n, 64), 256, 0, stream>>>(X3h, Wl1, bl1, Wl2, bl2, Wl3, bl3, out, n);
}

// Round 12
// 196.401 us; speedup vs baseline: 1.6244x; 1.0929x over previous
//
#include <hip/hip_runtime.h>

#define TPB 256
#define TE  2048      // edges per binscatter block
#define MAXB 6144     // fixed bucket capacity (mean 4081, 32 sigma headroom); mult of 8

typedef _Float16 half_t;
typedef _Float16 half4 __attribute__((ext_vector_type(4)));
typedef _Float16 half8 __attribute__((ext_vector_type(8)));
typedef float float8v __attribute__((ext_vector_type(8)));

static inline int cdiv(int a, int b) { return (a + b - 1) / b; }

// ---------------- CSR build ----------------
// Round-5 lesson: scattered 4B stores are ~16x write-amplified; all global
// writes are contiguous runs. Round-12: fixed-capacity buckets (base=b*MAXB)
// kill the histogram pass and both global scans.

__global__ void k_zero_int(int* p, int n) {
    int i = blockIdx.x * blockDim.x + threadIdx.x;
    if (i < n) p[i] = 0;
}

// bin edges into fixed bucket regions; one atomic reservation per (block,bucket)
__global__ void __launch_bounds__(TPB)
k_binscatter(const int* __restrict__ src, const int* __restrict__ dst,
             int* __restrict__ bcur, unsigned int* __restrict__ gbuf,
             int e, int nb) {
    __shared__ int lcnt[256], loffs[256], lcur[256], gres[256];
    __shared__ int ss[256];
    __shared__ unsigned int ldata[TE];
    const int tid = threadIdx.x;
    const int base = blockIdx.x * TE;
    const int cnt = min(TE, e - base);
    lcnt[tid] = 0;
    __syncthreads();

    unsigned int myv[TE / TPB];
    int myb[TE / TPB];
#pragma unroll
    for (int k = 0; k < TE / TPB; ++k) {
        int j = tid + k * TPB;
        if (j < cnt) {
            int d = dst[base + j], s = src[base + j];
            int b = d >> 8;
            myv[k] = ((unsigned)b << 24) | ((unsigned)(d & 255) << 16) | (unsigned)s;
            myb[k] = b;
            atomicAdd(&lcnt[b], 1);
        } else myb[k] = -1;
    }
    __syncthreads();
    {   // scan lcnt -> loffs/lcur
        int v = lcnt[tid];
        ss[tid] = v;
        __syncthreads();
        for (int d = 1; d < 256; d <<= 1) {
            int x2 = (tid >= d) ? ss[tid - d] : 0;
            __syncthreads();
            ss[tid] += x2;
            __syncthreads();
        }
        loffs[tid] = ss[tid] - v;
        lcur[tid] = ss[tid] - v;
    }
    __syncthreads();
    if (tid < nb && lcnt[tid])
        gres[tid] = tid * MAXB + atomicAdd(&bcur[tid], lcnt[tid]);
#pragma unroll
    for (int k = 0; k < TE / TPB; ++k) {
        if (myb[k] >= 0) {
            int p = atomicAdd(&lcur[myb[k]], 1);
            ldata[p] = myv[k];
        }
    }
    __syncthreads();
    for (int j = tid; j < cnt; j += TPB) {        // contiguous per-bucket runs
        unsigned int v = ldata[j];
        int b = v >> 24;
        gbuf[gres[b] + (j - loffs[b])] = v & 0xFFFFFFu;
    }
}

// per-bucket CSR: 8-aligned padded edge lists (sentinel = n -> zero G row),
// offs + nchunks + dinv, fused G16 = x*dinv scale. All writes coalesced.
__global__ void __launch_bounds__(TPB)
k_csr(const unsigned int* __restrict__ gbuf, const int* __restrict__ bcur,
      const float* __restrict__ x, int* __restrict__ offs,
      unsigned short* __restrict__ nch, float* __restrict__ dinv,
      unsigned short* __restrict__ ssrc, half_t* __restrict__ G, int n, int nb) {
    __shared__ int ss[256], cnt[256], loffs2[256], lcur2[256], pcnt[256];
    __shared__ float sdinv[256];
    __shared__ unsigned short stage[MAXB];
    const int b = blockIdx.x;
    const int t = threadIdx.x;
    const int s0 = b * MAXB;
    const int m = bcur[b];

    cnt[t] = 0;
    __syncthreads();
    for (int j = t; j < m; j += TPB)
        atomicAdd(&cnt[(gbuf[s0 + j] >> 16) & 255], 1);
    __syncthreads();
    {
        int v = cnt[t];
        int pv = (v + 7) & ~7;                        // pad to 8
        pcnt[t] = pv;
        ss[t] = pv;
        __syncthreads();
        for (int d = 1; d < 256; d <<= 1) {
            int x2 = (t >= d) ? ss[t - d] : 0;
            __syncthreads();
            ss[t] += x2;
            __syncthreads();
        }
        loffs2[t] = ss[t] - pv;
        lcur2[t] = ss[t] - pv;
        float di = rsqrtf((float)v + 1.0f);           // +1 self-loop
        sdinv[t] = di;
        int node = b * 256 + t;
        if (node < n) {
            offs[node] = s0 + loffs2[t];
            nch[node] = (unsigned short)(pv >> 3);
            dinv[node] = di;
        }
    }
    __syncthreads();
    for (int j = t; j < m; j += TPB) {
        unsigned int v = gbuf[s0 + j];
        int p = atomicAdd(&lcur2[(v >> 16) & 255], 1);
        stage[p] = (unsigned short)(v & 0xFFFFu);
    }
    __syncthreads();
    {   // sentinel-fill each node's padding (<=7 slots per node)
        int base2 = loffs2[t] + cnt[t], end2 = loffs2[t] + pcnt[t];
        for (int q = base2; q < end2; ++q) stage[q] = (unsigned short)n;
    }
    __syncthreads();
    const int tot = ss[255];                          // sum of padded counts
    for (int j = t; j < tot; j += TPB) ssrc[s0 + j] = stage[j];

    // fused scale: G16[node] = x[node] * dinv[node], fp32 -> fp16
    const int base = b * 256;
    const int cn = min(256, n - base);
    const float4* X4 = (const float4*)x;
    half4* G4 = (half4*)G;
    for (int j = t; j < cn * 4; j += TPB) {
        int nl = j >> 2, k4 = j & 3;
        float4 v = X4[(size_t)(base + nl) * 4 + k4];
        float d = sdinv[nl];
        half4 h;
        h.x = (half_t)(v.x * d); h.y = (half_t)(v.y * d);
        h.z = (half_t)(v.z * d); h.w = (half_t)(v.w * d);
        G4[(size_t)(base + nl) * 4 + k4] = h;
    }
    if (b == 0 && t < 4) G4[(size_t)n * 4 + t] = half4{0, 0, 0, 0};  // sentinel row
}

// ---------------- fused gather + GEMM conv ----------------
// r7: latency-bound -> deep unroll + launch_bounds(,4). r9: no degree sort.
// r10: no packed-fp16 GEMM (spills). r12: 8-aligned lists -> one uint4 load
// per 8 edge indices (9 VMEM/8 edges vs 16), no remainder loops.
template<int DI, int DO, int R, bool SCALE, bool OUT_HALF, bool WHALF, bool ZSENT>
__global__ void __launch_bounds__(TPB, 4)
k_conv(const int* __restrict__ offs, const unsigned short* __restrict__ nch,
       const unsigned short* __restrict__ ssrc,
       const half_t* __restrict__ G, const float* __restrict__ dinv,
       const float* __restrict__ W, const float* __restrict__ b,
       void* __restrict__ outp, int n) {
    constexpr int CT = DO / 4;
    constexpr int RT = TPB / CT;
    constexpr int TM = RT * R;
    constexpr int K4 = DI / 4;
    constexpr int PX = K4 + 1;       // padded pitch
    constexpr int C  = DI / 8;
    static_assert(TM * C == TPB, "gather/gemm tile mismatch");
    __shared__ float4 sW4[WHALF ? 1 : DI * CT];
    __shared__ half4  sWh[WHALF ? DI * CT : 1];
    __shared__ float4 sX4[TM * PX];
    __shared__ int soffs[TM];
    __shared__ unsigned short snch[TM];
    const int tid = threadIdx.x;
    const int r0 = blockIdx.x * TM;

    const float4* Wg = (const float4*)W;
    for (int t = tid; t < DI * CT; t += TPB) {
        float4 w = Wg[t];
        if (WHALF) {
            half4 h;
            h.x = (half_t)w.x; h.y = (half_t)w.y;
            h.z = (half_t)w.z; h.w = (half_t)w.w;
            sWh[t] = h;
        } else {
            sW4[t] = w;
        }
    }
    if (tid < TM) {
        int row = r0 + tid;
        soffs[tid] = (row < n) ? offs[row] : 0;
        snch[tid] = (row < n) ? nch[row] : (unsigned short)0;
    }
    __syncthreads();

    // ---- gather phase: each thread aggregates one half8 chunk of one row ----
    {
        int lrow = tid / C;
        int gc = tid - lrow * C;
        int row = r0 + lrow;
        float8v acc;
#pragma unroll
        for (int q = 0; q < 8; ++q) acc[q] = 0.f;
        if (row < n) {
            const half8* Grow = (const half8*)G;
            half8 hs = Grow[(size_t)row * C + gc];
#pragma unroll
            for (int q = 0; q < 8; ++q) acc[q] = (float)hs[q];
            const int nchunks = snch[lrow];
            const uint4* sv = (const uint4*)(ssrc + soffs[lrow]);   // 16B aligned
            for (int k = 0; k < nchunks; ++k) {
                uint4 pk = sv[k];                       // 8 edge indices
                int a0 = pk.x & 0xFFFF, a1 = pk.x >> 16;
                int a2 = pk.y & 0xFFFF, a3 = pk.y >> 16;
                int a4 = pk.z & 0xFFFF, a5 = pk.z >> 16;
                int a6 = pk.w & 0xFFFF, a7 = pk.w >> 16;
                half8 g0 = Grow[(size_t)a0 * C + gc];
                half8 g1 = Grow[(size_t)a1 * C + gc];
                half8 g2 = Grow[(size_t)a2 * C + gc];
                half8 g3 = Grow[(size_t)a3 * C + gc];
                half8 g4 = Grow[(size_t)a4 * C + gc];
                half8 g5 = Grow[(size_t)a5 * C + gc];
                half8 g6 = Grow[(size_t)a6 * C + gc];
                half8 g7 = Grow[(size_t)a7 * C + gc];
#pragma unroll
                for (int q = 0; q < 8; ++q)
                    acc[q] += (((float)g0[q] + (float)g1[q]) + ((float)g2[q] + (float)g3[q]))
                            + (((float)g4[q] + (float)g5[q]) + ((float)g6[q] + (float)g7[q]));
            }
            float di = dinv[row];
#pragma unroll
            for (int q = 0; q < 8; ++q) acc[q] *= di;
        }
        sX4[lrow * PX + 2 * gc]     = make_float4(acc[0], acc[1], acc[2], acc[3]);
        sX4[lrow * PX + 2 * gc + 1] = make_float4(acc[4], acc[5], acc[6], acc[7]);
    }
    __syncthreads();

    // ---- GEMM phase (fp32 LDS, round-8 proven) ----
    const int c = tid & (CT - 1);
    const int rg = tid / CT;
    const int rbase = rg * R;
    float4 acc[R];
#pragma unroll
    for (int r = 0; r < R; ++r) acc[r] = make_float4(0.f, 0.f, 0.f, 0.f);

#pragma unroll 2
    for (int k4 = 0; k4 < K4; ++k4) {
        float4 xv[R];
#pragma unroll
        for (int r = 0; r < R; ++r) xv[r] = sX4[(rbase + r) * PX + k4];
#pragma unroll
        for (int kk = 0; kk < 4; ++kk) {
            float4 wv;
            if (WHALF) {
                half4 wh = sWh[(k4 * 4 + kk) * CT + c];
                wv = make_float4((float)wh.x, (float)wh.y, (float)wh.z, (float)wh.w);
            } else {
                wv = sW4[(k4 * 4 + kk) * CT + c];
            }
#pragma unroll
            for (int r = 0; r < R; ++r) {
                float xs = (kk == 0) ? xv[r].x : (kk == 1) ? xv[r].y
                         : (kk == 2) ? xv[r].z : xv[r].w;
                acc[r].x += xs * wv.x; acc[r].y += xs * wv.y;
                acc[r].z += xs * wv.z; acc[r].w += xs * wv.w;
            }
        }
    }

    float4 bc = ((const float4*)b)[c];
#pragma unroll
    for (int r = 0; r < R; ++r) {
        int row = r0 + rbase + r;
        if (row < n) {
            float4 o;
            o.x = fmaxf(acc[r].x + bc.x, 0.f);
            o.y = fmaxf(acc[r].y + bc.y, 0.f);
            o.z = fmaxf(acc[r].z + bc.z, 0.f);
            o.w = fmaxf(acc[r].w + bc.w, 0.f);
            if (SCALE) {
                float d = dinv[row];
                o.x *= d; o.y *= d; o.z *= d; o.w *= d;
            }
            if (OUT_HALF) {
                half4 h;
                h.x = (half_t)o.x; h.y = (half_t)o.y;
                h.z = (half_t)o.z; h.w = (half_t)o.w;
                ((half4*)outp)[(size_t)row * CT + c] = h;
            } else {
                ((float4*)outp)[(size_t)row * CT + c] = o;
            }
        }
    }
    // zero the sentinel row of our output (next conv gathers it)
    if (ZSENT && OUT_HALF && blockIdx.x == 0 && tid < CT)
        ((half4*)outp)[(size_t)n * CT + tid] = half4{0, 0, 0, 0};
}

// ---------------- fused dense head (round-8 proven) ----------------
__global__ void __launch_bounds__(256, 2)
k_head(const half_t* __restrict__ X,
       const float* __restrict__ W1, const float* __restrict__ b1,
       const float* __restrict__ W2, const float* __restrict__ b2,
       const float* __restrict__ W3, const float* __restrict__ b3,
       float* __restrict__ out, int n) {
    __shared__ half_t hW1[128 * 64];
    __shared__ half_t hW2[64 * 32];
    __shared__ half_t hW3[32 * 16];
    __shared__ float h1[64 * 65];
    __shared__ float h2[64 * 33];
    const int tid = threadIdx.x;
    const int r0 = blockIdx.x * 64;

    for (int t = tid; t < 128 * 64; t += 256) hW1[t] = (half_t)W1[t];
    for (int t = tid; t < 64 * 32; t += 256) hW2[t] = (half_t)W2[t];
    for (int t = tid; t < 32 * 16; t += 256) hW3[t] = (half_t)W3[t];
    __syncthreads();

    // ---- stage 1: 128 -> 64 ----
    {
        const int c4 = tid & 15;
        const int rowg = tid >> 4;
        const half8* Xr = (const half8*)X;
        float acc[4][4];
#pragma unroll
        for (int r = 0; r < 4; ++r)
#pragma unroll
            for (int j = 0; j < 4; ++j) acc[r][j] = 0.f;
        for (int k8 = 0; k8 < 16; ++k8) {
            half8 xh[4];
#pragma unroll
            for (int r = 0; r < 4; ++r) {
                int row = r0 + rowg * 4 + r;
                if (row < n) xh[r] = Xr[(size_t)row * 16 + k8];
                else { half8 z; for (int q = 0; q < 8; ++q) z[q] = (half_t)0.f; xh[r] = z; }
            }
#pragma unroll
            for (int q = 0; q < 8; ++q) {
                int k = k8 * 8 + q;
                half4 w = *(const half4*)&hW1[k * 64 + c4 * 4];
                float w0 = (float)w.x, w1 = (float)w.y, w2 = (float)w.z, w3 = (float)w.w;
#pragma unroll
                for (int r = 0; r < 4; ++r) {
                    float xs = (float)xh[r][q];
                    acc[r][0] += xs * w0; acc[r][1] += xs * w1;
                    acc[r][2] += xs * w2; acc[r][3] += xs * w3;
                }
            }
        }
        float4 bc = ((const float4*)b1)[c4];
#pragma unroll
        for (int r = 0; r < 4; ++r) {
            int rl = rowg * 4 + r;
            h1[rl * 65 + c4 * 4 + 0] = fmaxf(acc[r][0] + bc.x, 0.f);
            h1[rl * 65 + c4 * 4 + 1] = fmaxf(acc[r][1] + bc.y, 0.f);
            h1[rl * 65 + c4 * 4 + 2] = fmaxf(acc[r][2] + bc.z, 0.f);
            h1[rl * 65 + c4 * 4 + 3] = fmaxf(acc[r][3] + bc.w, 0.f);
        }
    }
    __syncthreads();

    // ---- stage 2: 64 -> 32 ----
    {
        const int c4 = tid & 7;
        const int rowg = tid >> 3;
        float acc[2][4];
#pragma unroll
        for (int r = 0; r < 2; ++r)
#pragma unroll
            for (int j = 0; j < 4; ++j) acc[r][j] = 0.f;
#pragma unroll 4
        for (int k = 0; k < 64; ++k) {
            half4 w = *(const half4*)&hW2[k * 32 + c4 * 4];
            float w0 = (float)w.x, w1 = (float)w.y, w2 = (float)w.z, w3 = (float)w.w;
#pragma unroll
            for (int r = 0; r < 2; ++r) {
                float xs = h1[(rowg * 2 + r) * 65 + k];
                acc[r][0] += xs * w0; acc[r][1] += xs * w1;
                acc[r][2] += xs * w2; acc[r][3] += xs * w3;
            }
        }
        float4 bc = ((const float4*)b2)[c4];
#pragma unroll
        for (int r = 0; r < 2; ++r) {
            int rl = rowg * 2 + r;
            h2[rl * 33 + c4 * 4 + 0] = fmaxf(acc[r][0] + bc.x, 0.f);
            h2[rl * 33 + c4 * 4 + 1] = fmaxf(acc[r][1] + bc.y, 0.f);
            h2[rl * 33 + c4 * 4 + 2] = fmaxf(acc[r][2] + bc.z, 0.f);
            h2[rl * 33 + c4 * 4 + 3] = fmaxf(acc[r][3] + bc.w, 0.f);
        }
    }
    __syncthreads();

    // ---- stage 3: 32 -> 16 ----
    {
        const int c4 = tid & 3;
        const int rl = tid >> 2;
        float a0 = 0.f, a1 = 0.f, a2 = 0.f, a3 = 0.f;
#pragma unroll 4
        for (int k = 0; k < 32; ++k) {
            half4 w = *(const half4*)&hW3[k * 16 + c4 * 4];
            float xs = h2[rl * 33 + k];
            a0 += xs * (float)w.x; a1 += xs * (float)w.y;
            a2 += xs * (float)w.z; a3 += xs * (float)w.w;
        }
        int row = r0 + rl;
        if (row < n) {
            float4 bc = ((const float4*)b3)[c4];
            float4 o;
            o.x = fmaxf(a0 + bc.x, 0.f);
            o.y = fmaxf(a1 + bc.y, 0.f);
            o.z = fmaxf(a2 + bc.z, 0.f);
            o.w = fmaxf(a3 + bc.w, 0.f);
            ((float4*)out)[(size_t)row * 4 + c4] = o;
        }
    }
}

extern "C" void kernel_launch(void* const* d_in, const int* in_sizes, int n_in,
                              void* d_out, int out_size, void* d_ws, size_t ws_size,
                              hipStream_t stream) {
    const float* x   = (const float*)d_in[0];
    const int*   ei  = (const int*)d_in[1];
    const float* W1  = (const float*)d_in[2];
    const float* bb1 = (const float*)d_in[3];
    const float* W2  = (const float*)d_in[4];
    const float* bb2 = (const float*)d_in[5];
    const float* W3  = (const float*)d_in[6];
    const float* bb3 = (const float*)d_in[7];
    const float* Wl1 = (const float*)d_in[8];
    const float* bl1 = (const float*)d_in[9];
    const float* Wl2 = (const float*)d_in[10];
    const float* bl2 = (const float*)d_in[11];
    const float* Wl3 = (const float*)d_in[12];
    const float* bl3 = (const float*)d_in[13];
    float* out = (float*)d_out;

    const int n = in_sizes[0] / 16;   // 50000
    const int e = in_sizes[1] / 2;    // 800000
    const int* src = ei;
    const int* dst = ei + e;
    const int nb = cdiv(n, 256);      // 196 coarse buckets

    char* p = (char*)d_ws;
    auto alloc = [&](size_t bytes) {
        char* r = p;
        p += (bytes + 255) & ~(size_t)255;
        return r;
    };
    float*          dinv = (float*)         alloc((size_t)n * 4);
    int*            offs = (int*)           alloc((size_t)n * 4);
    unsigned short* nch  = (unsigned short*)alloc((size_t)n * 2);
    int*            bcur = (int*)           alloc(256 * 4);
    unsigned int*   gbuf = (unsigned int*)  alloc((size_t)nb * MAXB * 4);
    unsigned short* ssrc = (unsigned short*)alloc((size_t)nb * MAXB * 2);
    half_t*         H1   = (half_t*)        alloc((size_t)(n + 1) * 64 * 2); // G16/G64
    half_t*         H2   = (half_t*)        alloc((size_t)(n + 1) * 32 * 2);
    half_t*         X3h  = (half_t*)        alloc((size_t)n * 128 * 2);

    // ---- CSR + dinv + scaled G (fixed-capacity coalesced bucket sort) ----
    k_zero_int<<<1, 256, 0, stream>>>(bcur, 256);
    k_binscatter<<<cdiv(e, TE), TPB, 0, stream>>>(src, dst, bcur, gbuf, e, nb);
    k_csr<<<nb, TPB, 0, stream>>>(gbuf, bcur, x, offs, nch, dinv, ssrc, H1, n, nb);

    // ---- convs (fused gather+GEMM) ----
    k_conv<16, 32, 4, true, true, false, true><<<cdiv(n, 128), TPB, 0, stream>>>(
        offs, nch, ssrc, H1, dinv, W1, bb1, H2, n);
    k_conv<32, 64, 4, true, true, false, true><<<cdiv(n, 64), TPB, 0, stream>>>(
        offs, nch, ssrc, H2, dinv, W2, bb2, H1, n);
    k_conv<64, 128, 4, false, true, true, false><<<cdiv(n, 32), TPB, 0, stream>>>(
        offs, nch, ssrc, H1, dinv, W3, bb3, X3h, n);

    // ---- fused dense head ----
    k_head<<<cdiv(n, 64), 256, 0, stream>>>(X3h, Wl1, bl1, Wl2, bl2, Wl3, bl3, out, n);
}